// Round 17
// baseline (55.111 us; speedup 1.0000x reference)
//
#include <hip/hip_runtime.h>
#include <hip/hip_bf16.h>

#define BB 4096
#define DD 512
#define LLAB 20
#define NN 8192
#define KK 64

constexpr float kNegInf = -1.0e9f;
constexpr float kLn2 = 0.69314718055994530942f;
constexpr float kWlPe = 8.0f;    // per_ex safety band (i4 noise)
constexpr float kWlTie = 16.0f;  // accuracy near-tie band
constexpr double kFix = 1073741824.0;  // 2^30 fixed-point scale

// workspace layout (bytes)
#define OFF_STATS 16384                 // u32[8]: [0]=acc
#define OFF_MINPE 16640                 // u32[64] banked min-pe bits
#define OFF_SUMP  16896                 // u64[64] banked sum(pe)
#define OFF_SUMS  17408                 // u64[64] banked sum(pe*scale)
#define OFF_SP    36864
#define OFF_SIE   53248
#define OFF_SLE   69632
#define OFF_SALE  86016
#define OFF_HLAB  118784
#define OFF_HAL   151552
#define OFF_IEQ   217088
#define OFF_LEQ   (OFF_IEQ + (size_t)BB * 256)
#define OFF_ALEQ  (OFF_LEQ + (size_t)BB * 256)
#define WS_NEED   (OFF_ALEQ + (size_t)NN * 256)

typedef unsigned u32x4 __attribute__((ext_vector_type(4)));

__device__ __forceinline__ float dot4(const float4& a, const float4& b) {
  return a.x * b.x + a.y * b.y + a.z * b.z + a.w * b.w;
}

__device__ __forceinline__ float waveReduceSum(float v) {
#pragma unroll
  for (int s = 1; s < 64; s <<= 1) v += __shfl_xor(v, s);
  return v;
}

__device__ __forceinline__ float waveReduceMax(float v) {
#pragma unroll
  for (int s = 1; s < 64; s <<= 1) v = fmaxf(v, __shfl_xor(v, s));
  return v;
}

__device__ __forceinline__ float waveReduceMin(float v) {
#pragma unroll
  for (int s = 1; s < 64; s <<= 1) v = fminf(v, __shfl_xor(v, s));
  return v;
}

__device__ __forceinline__ unsigned long long hash20(const float* __restrict__ p) {
  unsigned long long h = 1469598103934665603ull;
#pragma unroll
  for (int t = 0; t < LLAB; ++t) {
    h ^= (unsigned long long)__float_as_uint(p[t]);
    h *= 1099511628211ull;
  }
  return h;
}

// i4x8 dot with i32 accumulate (v_dot8_i32_i4).
__device__ __forceinline__ int sdot8i(unsigned a, unsigned b, int acc) {
#if __has_builtin(__builtin_amdgcn_sdot8)
  return __builtin_amdgcn_sdot8((int)a, (int)b, acc, false);
#else
#pragma unroll
  for (int t = 0; t < 8; ++t) {
    const int av = ((int)(a << (28 - 4 * t))) >> 28;
    const int bv = ((int)(b << (28 - 4 * t))) >> 28;
    acc += av * bv;
  }
  return acc;
#endif
}

// pack 8 floats into one u32 of signed nibbles (|x*inv| <= 7 by construction).
__device__ __forceinline__ unsigned pk8i4(const float4& a, const float4& b, float inv) {
  unsigned w = 0;
  w |= ((unsigned)((int)rintf(a.x * inv) & 0xF));
  w |= ((unsigned)((int)rintf(a.y * inv) & 0xF)) << 4;
  w |= ((unsigned)((int)rintf(a.z * inv) & 0xF)) << 8;
  w |= ((unsigned)((int)rintf(a.w * inv) & 0xF)) << 12;
  w |= ((unsigned)((int)rintf(b.x * inv) & 0xF)) << 16;
  w |= ((unsigned)((int)rintf(b.y * inv) & 0xF)) << 20;
  w |= ((unsigned)((int)rintf(b.z * inv) & 0xF)) << 24;
  w |= ((unsigned)((int)rintf(b.w * inv) & 0xF)) << 28;
  return w;
}

__device__ __forceinline__ float max8abs(const float4& a, const float4& c) {
  return fmaxf(fmaxf(fmaxf(fabsf(a.x), fabsf(a.y)), fmaxf(fabsf(a.z), fabsf(a.w))),
               fmaxf(fmaxf(fabsf(c.x), fabsf(c.y)), fmaxf(fabsf(c.z), fabsf(c.w))));
}

__device__ __forceinline__ float loss_scale(float pe) {
  const float q = expf(-pe);
  const float t = 2.0f * (1.0f - q);
  const float t2 = t * t;
  return t2 * t2;
}

// Deterministic order-independent accumulation (fixed point 2^30).
__device__ __forceinline__ void accum_loss(int b, float pe, unsigned* minpeB,
                                           unsigned long long* sumP,
                                           unsigned long long* sumS) {
  const float pc = fmaxf(pe, 0.0f);
  const int bank = b & 63;
  atomicMin(&minpeB[bank], __float_as_uint(pc));
  atomicAdd(&sumP[bank], (unsigned long long)((double)pc * kFix + 0.5));
  atomicAdd(&sumS[bank],
            (unsigned long long)((double)(pc * loss_scale(pc)) * kFix + 0.5));
}

__global__ void init_kernel(unsigned* stats) {
  if (threadIdx.x == 0) stats[0] = 0u;
}

// Prep (one wave per row): i4-quantize ie+le (w<BB) with exact sim_pos, or
// ale; hash both label tables; init stats/banks.
__global__ __launch_bounds__(256) void prep_kernel(
    const float* __restrict__ ie, const float* __restrict__ le,
    const float* __restrict__ ale, const float* __restrict__ labels,
    const float* __restrict__ al, unsigned* __restrict__ ie_q,
    unsigned* __restrict__ le_q, unsigned* __restrict__ ale_q,
    float* __restrict__ s_ie, float* __restrict__ s_le,
    float* __restrict__ s_ale, float* __restrict__ sp,
    unsigned long long* __restrict__ h_lab,
    unsigned long long* __restrict__ h_al, unsigned* __restrict__ stats,
    unsigned* __restrict__ minpeB, unsigned long long* __restrict__ sumP,
    unsigned long long* __restrict__ sumS) {
  const int tid = threadIdx.x;
  const int lane = tid & 63;
  const int wave = tid >> 6;
  const int w = blockIdx.x * 4 + wave;

  if (w < BB) {
    const float4* i4p = (const float4*)(ie + (size_t)w * DD);
    const float4* l4p = (const float4*)(le + (size_t)w * DD);
    const float4 a0 = i4p[2 * lane], a1 = i4p[2 * lane + 1];
    const float4 b0 = l4p[2 * lane], b1 = l4p[2 * lane + 1];
    float p = dot4(a0, b0) + dot4(a1, b1);
    p = waveReduceSum(p);
    float mi = fmaxf(waveReduceMax(max8abs(a0, a1)), 1e-20f);
    ie_q[(size_t)w * 64 + lane] = pk8i4(a0, a1, 7.0f / mi);
    float ml = fmaxf(waveReduceMax(max8abs(b0, b1)), 1e-20f);
    le_q[(size_t)w * 64 + lane] = pk8i4(b0, b1, 7.0f / ml);
    if (lane == 0) {
      sp[w] = p;
      s_ie[w] = mi * (1.0f / 7.0f);
      s_le[w] = ml * (1.0f / 7.0f);
    }
  } else {
    const int row = w - BB;
    const float4* r4 = (const float4*)(ale + (size_t)row * DD);
    const float4 a = r4[2 * lane], c = r4[2 * lane + 1];
    float mx = fmaxf(waveReduceMax(max8abs(a, c)), 1e-20f);
    ale_q[(size_t)row * 64 + lane] = pk8i4(a, c, 7.0f / mx);
    if (lane == 0) s_ale[row] = mx * (1.0f / 7.0f);
  }

  const int g = blockIdx.x * 256 + tid;
  if (g < 2) stats[g] = 0u;
  if (g < 64) {
    minpeB[g] = 0x7F800000u;  // +inf
    sumP[g] = 0ull;
    sumS[g] = 0ull;
  }
  if (g < BB) h_lab[g] = hash20(labels + (size_t)g * LLAB);
  else if (g < BB + NN) h_al[g - BB] = hash20(al + (size_t)(g - BB) * LLAB);
}

// Exact f32 row compute (fallback + in-kernel fixup path).
__device__ __forceinline__ void row_f32_body(
    int b, const float* __restrict__ ie, const float* __restrict__ le,
    const float* __restrict__ labels, const float* __restrict__ ale,
    const float* __restrict__ al, const int* __restrict__ nin,
    const int* __restrict__ nlb, float* __restrict__ per_ex,
    unsigned* __restrict__ stats, bool count_acc, float* sims, float* wred) {
  const int tid = threadIdx.x;
  const int lane = tid & 63;
  const int wave = tid >> 6;

  const float4* ie4 = (const float4*)(ie + (size_t)b * DD);
  const float4* le4 = (const float4*)(le + (size_t)b * DD);
  float4 ier0 = ie4[lane], ier1 = ie4[lane + 64];
  float4 ler0 = le4[lane], ler1 = le4[lane + 64];
  float lab = (lane < LLAB) ? labels[(size_t)b * LLAB + lane] : 0.0f;

  if (wave == 0) {
    float p = dot4(ier0, ler0) + dot4(ier1, ler1);
    p = waveReduceSum(p);
    if (lane == 0) sims[0] = p;
  }

#pragma unroll 2
  for (int kk = 0; kk < KK / 4; ++kk) {
    const int k = wave * (KK / 4) + kk;
    const int j_lb = __builtin_amdgcn_readfirstlane(nlb[(size_t)b * KK + k]);
    const int j_in = __builtin_amdgcn_readfirstlane(nin[(size_t)b * KK + k]);

    const float4* rle = (const float4*)(ale + (size_t)j_lb * DD);
    const float4* rie = (const float4*)(ie + (size_t)j_in * DD);
    float4 vle0 = rle[lane], vle1 = rle[lane + 64];
    float4 vie0 = rie[lane], vie1 = rie[lane + 64];

    bool ein = true, elb = true;
    if (lane < LLAB) {
      ein = (labels[(size_t)j_in * LLAB + lane] == lab);
      elb = (al[(size_t)j_lb * LLAB + lane] == lab);
    }
    const bool bad_in = (__ballot(ein) == ~0ull);
    const bool bad_lb = (__ballot(elb) == ~0ull);

    float a_il = dot4(vle0, ier0) + dot4(vle1, ier1);
    float a_ll = dot4(vle0, ler0) + dot4(vle1, ler1);
    float a_ii = dot4(vie0, ier0) + dot4(vie1, ier1);
    float a_li = dot4(vie0, ler0) + dot4(vie1, ler1);

    const bool oddl = (lane & 1) != 0;
    float sx = oddl ? a_il : a_ii;
    float sy = oddl ? a_ll : a_li;
    float rx = __shfl_xor(sx, 1);
    float ry = __shfl_xor(sy, 1);
    float mx = (oddl ? a_ii : a_il) + rx;
    float my = (oddl ? a_li : a_ll) + ry;
    const bool hi2 = (lane & 2) != 0;
    float s1 = hi2 ? mx : my;
    float r1 = __shfl_xor(s1, 2);
    float v = (hi2 ? my : mx) + r1;
    v += __shfl_xor(v, 4);
    v += __shfl_xor(v, 8);
    v += __shfl_xor(v, 16);
    v += __shfl_xor(v, 32);

    if (lane < 4) {
      const bool badf = (lane & 1) ? bad_in : bad_lb;
      const float s = badf ? v + kNegInf : v;
      const int slot = ((lane & 1) << 1) | ((lane >> 1) & 1);
      sims[1 + slot * KK + k] = s;
    }
  }
  __syncthreads();

  const float v = sims[1 + tid];
  const float s0 = sims[0];
  float wmax = waveReduceMax(v);
  if (lane == 0) wred[wave] = wmax;
  __syncthreads();
  float m = fmaxf(fmaxf(wred[0], wred[1]), fmaxf(wred[2], wred[3]));
  m = fmaxf(m, s0);
  const float e = expf(v - m);
  float wsum = waveReduceSum(e);
  if (lane == 0) wred[4 + wave] = wsum;
  __syncthreads();
  if (tid == 0) {
    const float tot = wred[4] + wred[5] + wred[6] + wred[7] + expf(s0 - m);
    per_ex[b] = m + logf(tot) - s0;
    if (count_acc) {
      const float max_il = wred[0];
      if (s0 >= max_il) atomicAdd(&stats[0], 1u);
    }
  }
}

// Main pass: one 256-thread block per row b; each 4-lane quad owns one
// negative k. i4 tables: 256B/row, 4x dwordx4 per table row per quad,
// 64 sdot8/lane. Band rows self-fix exactly; banked loss accumulation.
// launch_bounds(256,4): the (256,8) variant squeezes VGPR to 32 and
// serializes the 8 in-flight gather buffers (r16: +5 us regression).
__global__ __launch_bounds__(256, 4) void row_i4_kernel(
    const float* __restrict__ ie, const float* __restrict__ le,
    const float* __restrict__ labels, const float* __restrict__ ale,
    const float* __restrict__ al, const unsigned* __restrict__ ie_q,
    const unsigned* __restrict__ le_q, const unsigned* __restrict__ ale_q,
    const float* __restrict__ s_ie, const float* __restrict__ s_le,
    const float* __restrict__ s_ale, const float* __restrict__ sp,
    const unsigned long long* __restrict__ h_lab,
    const unsigned long long* __restrict__ h_al,
    const int* __restrict__ nin, const int* __restrict__ nlb,
    float* __restrict__ per_ex, unsigned* __restrict__ stats,
    unsigned* __restrict__ minpeB, unsigned long long* __restrict__ sumP,
    unsigned long long* __restrict__ sumS) {
  const int b = blockIdx.x;
  const int tid = threadIdx.x;
  const int lane = tid & 63;
  const int wave = tid >> 6;
  const int c = lane & 3;
  const int g = lane >> 2;

  __shared__ unsigned qu[128];         // qi4 (64 u32) + ql4 (64 u32)
  __shared__ float simsX[1 + 4 * KK];  // exact fixup path only
  __shared__ float wred[12];
  __shared__ int do_fix;

  // Indices + gather loads issued first (before staging barrier).
  const int wuni = __builtin_amdgcn_readfirstlane(wave);
  const int k = wuni * 16 + g;
  const int jl = nlb[b * KK + k];
  const int ji = nin[b * KK + k];

  const u32x4* pa = (const u32x4*)(ale_q + ((size_t)jl << 6)) + c;
  const u32x4* pb = (const u32x4*)(ie_q + ((size_t)ji << 6)) + c;
  const u32x4 A0 = pa[0], A1 = pa[4], A2 = pa[8], A3 = pa[12];
  const u32x4 B0 = pb[0], B1 = pb[4], B2 = pb[8], B3 = pb[12];

  const unsigned long long hb = h_lab[b];
  const bool bad_lb = (h_al[jl] == hb);
  const bool bad_in = (h_lab[ji] == hb);
  const float sA = s_ale[jl];
  const float sB = s_ie[ji];
  const float s0 = sp[b];
  const float sqi = s_ie[b];
  const float sql = s_le[b];

  // Stage the two 256B quantized query rows to LDS (first wave).
  if (wave == 0) {
    qu[lane] = ie_q[((size_t)b << 6) + lane];
    qu[64 + lane] = le_q[((size_t)b << 6) + lane];
  }
  __syncthreads();

  // 64 sdot8 per lane, 4 independent accumulators.
  int il = 0, ll = 0, ii = 0, li = 0;
#define STEP(Ai, Bi, i)                                                \
  {                                                                    \
    const int qb = 4 * c + 16 * (i);                                   \
    const unsigned q0 = qu[qb], q1 = qu[qb + 1];                       \
    const unsigned q2 = qu[qb + 2], q3 = qu[qb + 3];                   \
    const unsigned l0 = qu[64 + qb], l1 = qu[64 + qb + 1];             \
    const unsigned l2 = qu[64 + qb + 2], l3 = qu[64 + qb + 3];         \
    il = sdot8i(Ai.x, q0, il); il = sdot8i(Ai.y, q1, il);              \
    il = sdot8i(Ai.z, q2, il); il = sdot8i(Ai.w, q3, il);              \
    ll = sdot8i(Ai.x, l0, ll); ll = sdot8i(Ai.y, l1, ll);              \
    ll = sdot8i(Ai.z, l2, ll); ll = sdot8i(Ai.w, l3, ll);              \
    ii = sdot8i(Bi.x, q0, ii); ii = sdot8i(Bi.y, q1, ii);              \
    ii = sdot8i(Bi.z, q2, ii); ii = sdot8i(Bi.w, q3, ii);              \
    li = sdot8i(Bi.x, l0, li); li = sdot8i(Bi.y, l1, li);              \
    li = sdot8i(Bi.z, l2, li); li = sdot8i(Bi.w, l3, li);              \
  }
  STEP(A0, B0, 0) STEP(A1, B1, 1) STEP(A2, B2, 2) STEP(A3, B3, 3)
#undef STEP

  // 2-shfl component-split within the quad; c: 0->il 1->ii 2->ll 3->li
  const bool odd = (lane & 1) != 0;
  const int x = odd ? il : ii;
  const int y = odd ? ll : li;
  const int rx = __shfl_xor(x, 1);
  const int ry = __shfl_xor(y, 1);
  const int aa = (odd ? ii : il) + rx;
  const int bb2 = (odd ? li : ll) + ry;
  const bool hi2 = (lane & 2) != 0;
  const int s1 = hi2 ? aa : bb2;
  const int r1 = __shfl_xor(s1, 2);
  const int vi = (hi2 ? bb2 : aa) + r1;

  const float srow = (c & 1) ? sB : sA;
  const float sq = (c & 2) ? sql : sqi;
  const float v = (float)vi * (srow * sq);
  const bool badf = (c & 1) ? bad_in : bad_lb;
  const float s = badf ? v + kNegInf : v;

  // Block LSE from lane-resident sims.
  float m_w = waveReduceMax(s);
  float mil_w = waveReduceMax((c == 0) ? s : -3.0e38f);
  if (lane == 0) {
    wred[wave] = m_w;
    wred[4 + wave] = mil_w;
  }
  __syncthreads();
  float m = fmaxf(fmaxf(fmaxf(wred[0], wred[1]), fmaxf(wred[2], wred[3])), s0);
  const float e = expf(s - m);
  float sum_w = waveReduceSum(e);
  if (lane == 0) wred[8 + wave] = sum_w;
  __syncthreads();
  if (tid == 0) {
    const float tot = wred[8] + wred[9] + wred[10] + wred[11] + expf(s0 - m);
    const float pe = m + logf(tot) - s0;
    per_ex[b] = pe;
    const float max_il = fmaxf(fmaxf(wred[4], wred[5]), fmaxf(wred[6], wred[7]));
    const bool wl_row = (pe < kWlPe) || (fabsf(s0 - max_il) < kWlTie);
    do_fix = wl_row ? 1 : 0;
    if (!wl_row) {
      if (s0 >= max_il) atomicAdd(&stats[0], 1u);
      accum_loss(b, pe, minpeB, sumP, sumS);
    }
  }
  __syncthreads();

  // Band rows: exact f32 recompute (per_ex + acc) within this block.
  if (do_fix) {
    row_f32_body(b, ie, le, labels, ale, al, nin, nlb, per_ex, stats,
                 true, simsX, wred);
    if (tid == 0) accum_loss(b, per_ex[b], minpeB, sumP, sumS);
  }
}

// Fallback: full exact pass (used only if ws too small).
__global__ __launch_bounds__(256) void row_f32_kernel(
    const float* __restrict__ ie, const float* __restrict__ le,
    const float* __restrict__ labels, const float* __restrict__ ale,
    const float* __restrict__ al, const int* __restrict__ nin,
    const int* __restrict__ nlb, float* __restrict__ per_ex,
    unsigned* __restrict__ stats) {
  __shared__ float sims[1 + 4 * KK];
  __shared__ float wred[8];
  row_f32_body(blockIdx.x, ie, le, labels, ale, al, nin, nlb, per_ex, stats,
               true, sims, wred);
}

// Tiny finalize: 1 wave reduces the 64 banks.
__global__ __launch_bounds__(64) void finalize2_kernel(
    const unsigned* __restrict__ stats, const unsigned* __restrict__ minpeB,
    const unsigned long long* __restrict__ sumP,
    const unsigned long long* __restrict__ sumS, float* __restrict__ out) {
  const int lane = threadIdx.x;
  unsigned mb = minpeB[lane];
  unsigned long long p = sumP[lane];
  unsigned long long q = sumS[lane];
#pragma unroll
  for (int s = 1; s < 64; s <<= 1) {
    mb = min(mb, (unsigned)__shfl_xor((int)mb, s));
    p += (unsigned long long)__shfl_xor((long long)p, s);
    q += (unsigned long long)__shfl_xor((long long)q, s);
  }
  if (lane == 0) {
    const float minpe = __uint_as_float(mb);
    const bool scale_on = (minpe < kLn2);  // max(q) > 0.5
    const double tot = (double)(scale_on ? q : p) / kFix;
    out[0] = (float)(tot / (double)BB);
    out[1] = (float)stats[0] / (float)BB;
  }
}

// Fallback finalize (per_ex based).
__global__ __launch_bounds__(256) void finalize_kernel(
    const float* __restrict__ per_ex, const unsigned* __restrict__ stats,
    float* __restrict__ out) {
  __shared__ float pe_s[BB];
  __shared__ float wred[8];
  const int tid = threadIdx.x;
  const int lane = tid & 63;
  const int wave = tid >> 6;

  float mn = 1.0e30f;
#pragma unroll 4
  for (int i = tid; i < BB; i += 256) {
    const float v = per_ex[i];
    pe_s[i] = v;
    mn = fminf(mn, v);
  }
  mn = waveReduceMin(mn);
  if (lane == 0) wred[wave] = mn;
  __syncthreads();
  const float minpe = fminf(fminf(wred[0], wred[1]), fminf(wred[2], wred[3]));
  const bool scale_on = (minpe < kLn2);
  __syncthreads();

  float sum = 0.0f;
#pragma unroll 4
  for (int i = tid; i < BB; i += 256) {
    const float pe = pe_s[i];
    sum += pe * (scale_on ? loss_scale(pe) : 1.0f);
  }
  sum = waveReduceSum(sum);
  if (lane == 0) wred[4 + wave] = sum;
  __syncthreads();
  if (tid == 0) {
    const float tot = wred[4] + wred[5] + wred[6] + wred[7];
    out[0] = tot / (float)BB;
    out[1] = (float)stats[0] / (float)BB;
  }
}

extern "C" void kernel_launch(void* const* d_in, const int* in_sizes, int n_in,
                              void* d_out, int out_size, void* d_ws, size_t ws_size,
                              hipStream_t stream) {
  const float* ie = (const float*)d_in[0];
  const float* le = (const float*)d_in[1];
  const float* labels = (const float*)d_in[2];
  const float* ale = (const float*)d_in[3];
  const float* al = (const float*)d_in[4];
  const int* nin = (const int*)d_in[5];
  const int* nlb = (const int*)d_in[6];
  float* out = (float*)d_out;

  float* per_ex = (float*)d_ws;
  unsigned* stats = (unsigned*)((char*)d_ws + OFF_STATS);

  if (ws_size >= WS_NEED) {
    unsigned* ie_q = (unsigned*)((char*)d_ws + OFF_IEQ);
    unsigned* le_q = (unsigned*)((char*)d_ws + OFF_LEQ);
    unsigned* ale_q = (unsigned*)((char*)d_ws + OFF_ALEQ);
    float* s_ie = (float*)((char*)d_ws + OFF_SIE);
    float* s_le = (float*)((char*)d_ws + OFF_SLE);
    float* s_ale = (float*)((char*)d_ws + OFF_SALE);
    float* sp = (float*)((char*)d_ws + OFF_SP);
    unsigned long long* h_lab = (unsigned long long*)((char*)d_ws + OFF_HLAB);
    unsigned long long* h_al = (unsigned long long*)((char*)d_ws + OFF_HAL);
    unsigned* minpeB = (unsigned*)((char*)d_ws + OFF_MINPE);
    unsigned long long* sumP = (unsigned long long*)((char*)d_ws + OFF_SUMP);
    unsigned long long* sumS = (unsigned long long*)((char*)d_ws + OFF_SUMS);

    const int prep_blocks = (BB + NN) / 4;
    hipLaunchKernelGGL(prep_kernel, dim3(prep_blocks), dim3(256), 0, stream,
                       ie, le, ale, labels, al, ie_q, le_q, ale_q,
                       s_ie, s_le, s_ale, sp, h_lab, h_al, stats,
                       minpeB, sumP, sumS);
    hipLaunchKernelGGL(row_i4_kernel, dim3(BB), dim3(256), 0, stream,
                       ie, le, labels, ale, al, ie_q, le_q, ale_q,
                       s_ie, s_le, s_ale, sp, h_lab, h_al, nin, nlb,
                       per_ex, stats, minpeB, sumP, sumS);
    hipLaunchKernelGGL(finalize2_kernel, dim3(1), dim3(64), 0, stream,
                       stats, minpeB, sumP, sumS, out);
  } else {
    hipLaunchKernelGGL(init_kernel, dim3(1), dim3(64), 0, stream, stats);
    hipLaunchKernelGGL(row_f32_kernel, dim3(BB), dim3(256), 0, stream,
                       ie, le, labels, ale, al, nin, nlb, per_ex, stats);
    hipLaunchKernelGGL(finalize_kernel, dim3(1), dim3(256), 0, stream,
                       per_ex, stats, out);
  }
}

// Round 18
// 47.978 us; speedup vs baseline: 1.1487x; 1.1487x over previous
//
#include <hip/hip_runtime.h>
#include <hip/hip_bf16.h>

#define BB 4096
#define DD 512
#define LLAB 20
#define NN 8192
#define KK 64

constexpr float kNegInf = -1.0e9f;
constexpr float kLn2 = 0.69314718055994530942f;
constexpr float kWlPe = 8.0f;    // per_ex safety band (i4 noise)
constexpr float kWlTie = 16.0f;  // accuracy near-tie band

// workspace layout (bytes)
#define OFF_STATS 16384
#define OFF_SP    36864
#define OFF_SIE   53248
#define OFF_SLE   69632
#define OFF_SALE  86016
#define OFF_HLAB  118784
#define OFF_HAL   151552
#define OFF_IEQ   217088
#define OFF_LEQ   (OFF_IEQ + (size_t)BB * 256)
#define OFF_ALEQ  (OFF_LEQ + (size_t)BB * 256)
#define WS_NEED   (OFF_ALEQ + (size_t)NN * 256)

typedef unsigned u32x4 __attribute__((ext_vector_type(4)));

__device__ __forceinline__ float dot4(const float4& a, const float4& b) {
  return a.x * b.x + a.y * b.y + a.z * b.z + a.w * b.w;
}

__device__ __forceinline__ float waveReduceSum(float v) {
#pragma unroll
  for (int s = 1; s < 64; s <<= 1) v += __shfl_xor(v, s);
  return v;
}

__device__ __forceinline__ float waveReduceMax(float v) {
#pragma unroll
  for (int s = 1; s < 64; s <<= 1) v = fmaxf(v, __shfl_xor(v, s));
  return v;
}

__device__ __forceinline__ float waveReduceMin(float v) {
#pragma unroll
  for (int s = 1; s < 64; s <<= 1) v = fminf(v, __shfl_xor(v, s));
  return v;
}

__device__ __forceinline__ unsigned long long hash20(const float* __restrict__ p) {
  unsigned long long h = 1469598103934665603ull;
#pragma unroll
  for (int t = 0; t < LLAB; ++t) {
    h ^= (unsigned long long)__float_as_uint(p[t]);
    h *= 1099511628211ull;
  }
  return h;
}

// i4x8 dot with i32 accumulate (v_dot8_i32_i4).
__device__ __forceinline__ int sdot8i(unsigned a, unsigned b, int acc) {
#if __has_builtin(__builtin_amdgcn_sdot8)
  return __builtin_amdgcn_sdot8((int)a, (int)b, acc, false);
#else
#pragma unroll
  for (int t = 0; t < 8; ++t) {
    const int av = ((int)(a << (28 - 4 * t))) >> 28;
    const int bv = ((int)(b << (28 - 4 * t))) >> 28;
    acc += av * bv;
  }
  return acc;
#endif
}

// pack 8 floats into one u32 of signed nibbles (|x*inv| <= 7 by construction).
__device__ __forceinline__ unsigned pk8i4(const float4& a, const float4& b, float inv) {
  unsigned w = 0;
  w |= ((unsigned)((int)rintf(a.x * inv) & 0xF));
  w |= ((unsigned)((int)rintf(a.y * inv) & 0xF)) << 4;
  w |= ((unsigned)((int)rintf(a.z * inv) & 0xF)) << 8;
  w |= ((unsigned)((int)rintf(a.w * inv) & 0xF)) << 12;
  w |= ((unsigned)((int)rintf(b.x * inv) & 0xF)) << 16;
  w |= ((unsigned)((int)rintf(b.y * inv) & 0xF)) << 20;
  w |= ((unsigned)((int)rintf(b.z * inv) & 0xF)) << 24;
  w |= ((unsigned)((int)rintf(b.w * inv) & 0xF)) << 28;
  return w;
}

__device__ __forceinline__ float max8abs(const float4& a, const float4& c) {
  return fmaxf(fmaxf(fmaxf(fabsf(a.x), fabsf(a.y)), fmaxf(fabsf(a.z), fabsf(a.w))),
               fmaxf(fmaxf(fabsf(c.x), fabsf(c.y)), fmaxf(fabsf(c.z), fabsf(c.w))));
}

__device__ __forceinline__ float loss_scale(float pe) {
  const float q = expf(-pe);
  const float t = 2.0f * (1.0f - q);
  const float t2 = t * t;
  return t2 * t2;
}

__global__ void init_kernel(unsigned* stats) {
  if (threadIdx.x == 0) stats[0] = 0u;
}

// Prep (one wave per row): i4-quantize ie+le (w<BB) with exact sim_pos, or
// ale; hash both label tables; init stats.
__global__ __launch_bounds__(256) void prep_kernel(
    const float* __restrict__ ie, const float* __restrict__ le,
    const float* __restrict__ ale, const float* __restrict__ labels,
    const float* __restrict__ al, unsigned* __restrict__ ie_q,
    unsigned* __restrict__ le_q, unsigned* __restrict__ ale_q,
    float* __restrict__ s_ie, float* __restrict__ s_le,
    float* __restrict__ s_ale, float* __restrict__ sp,
    unsigned long long* __restrict__ h_lab,
    unsigned long long* __restrict__ h_al, unsigned* __restrict__ stats) {
  const int tid = threadIdx.x;
  const int lane = tid & 63;
  const int wave = tid >> 6;
  const int w = blockIdx.x * 4 + wave;

  if (w < BB) {
    const float4* i4p = (const float4*)(ie + (size_t)w * DD);
    const float4* l4p = (const float4*)(le + (size_t)w * DD);
    const float4 a0 = i4p[2 * lane], a1 = i4p[2 * lane + 1];
    const float4 b0 = l4p[2 * lane], b1 = l4p[2 * lane + 1];
    float p = dot4(a0, b0) + dot4(a1, b1);
    p = waveReduceSum(p);
    float mi = fmaxf(waveReduceMax(max8abs(a0, a1)), 1e-20f);
    ie_q[(size_t)w * 64 + lane] = pk8i4(a0, a1, 7.0f / mi);
    float ml = fmaxf(waveReduceMax(max8abs(b0, b1)), 1e-20f);
    le_q[(size_t)w * 64 + lane] = pk8i4(b0, b1, 7.0f / ml);
    if (lane == 0) {
      sp[w] = p;
      s_ie[w] = mi * (1.0f / 7.0f);
      s_le[w] = ml * (1.0f / 7.0f);
    }
  } else {
    const int row = w - BB;
    const float4* r4 = (const float4*)(ale + (size_t)row * DD);
    const float4 a = r4[2 * lane], c = r4[2 * lane + 1];
    float mx = fmaxf(waveReduceMax(max8abs(a, c)), 1e-20f);
    ale_q[(size_t)row * 64 + lane] = pk8i4(a, c, 7.0f / mx);
    if (lane == 0) s_ale[row] = mx * (1.0f / 7.0f);
  }

  const int g = blockIdx.x * 256 + tid;
  if (g < 2) stats[g] = 0u;
  if (g < BB) h_lab[g] = hash20(labels + (size_t)g * LLAB);
  else if (g < BB + NN) h_al[g - BB] = hash20(al + (size_t)(g - BB) * LLAB);
}

// Exact f32 row compute (fallback + in-kernel fixup path).
__device__ __forceinline__ void row_f32_body(
    int b, const float* __restrict__ ie, const float* __restrict__ le,
    const float* __restrict__ labels, const float* __restrict__ ale,
    const float* __restrict__ al, const int* __restrict__ nin,
    const int* __restrict__ nlb, float* __restrict__ per_ex,
    unsigned* __restrict__ stats, bool count_acc, float* sims, float* wred) {
  const int tid = threadIdx.x;
  const int lane = tid & 63;
  const int wave = tid >> 6;

  const float4* ie4 = (const float4*)(ie + (size_t)b * DD);
  const float4* le4 = (const float4*)(le + (size_t)b * DD);
  float4 ier0 = ie4[lane], ier1 = ie4[lane + 64];
  float4 ler0 = le4[lane], ler1 = le4[lane + 64];
  float lab = (lane < LLAB) ? labels[(size_t)b * LLAB + lane] : 0.0f;

  if (wave == 0) {
    float p = dot4(ier0, ler0) + dot4(ier1, ler1);
    p = waveReduceSum(p);
    if (lane == 0) sims[0] = p;
  }

#pragma unroll 2
  for (int kk = 0; kk < KK / 4; ++kk) {
    const int k = wave * (KK / 4) + kk;
    const int j_lb = __builtin_amdgcn_readfirstlane(nlb[(size_t)b * KK + k]);
    const int j_in = __builtin_amdgcn_readfirstlane(nin[(size_t)b * KK + k]);

    const float4* rle = (const float4*)(ale + (size_t)j_lb * DD);
    const float4* rie = (const float4*)(ie + (size_t)j_in * DD);
    float4 vle0 = rle[lane], vle1 = rle[lane + 64];
    float4 vie0 = rie[lane], vie1 = rie[lane + 64];

    bool ein = true, elb = true;
    if (lane < LLAB) {
      ein = (labels[(size_t)j_in * LLAB + lane] == lab);
      elb = (al[(size_t)j_lb * LLAB + lane] == lab);
    }
    const bool bad_in = (__ballot(ein) == ~0ull);
    const bool bad_lb = (__ballot(elb) == ~0ull);

    float a_il = dot4(vle0, ier0) + dot4(vle1, ier1);
    float a_ll = dot4(vle0, ler0) + dot4(vle1, ler1);
    float a_ii = dot4(vie0, ier0) + dot4(vie1, ier1);
    float a_li = dot4(vie0, ler0) + dot4(vie1, ler1);

    const bool oddl = (lane & 1) != 0;
    float sx = oddl ? a_il : a_ii;
    float sy = oddl ? a_ll : a_li;
    float rx = __shfl_xor(sx, 1);
    float ry = __shfl_xor(sy, 1);
    float mx = (oddl ? a_ii : a_il) + rx;
    float my = (oddl ? a_li : a_ll) + ry;
    const bool hi2 = (lane & 2) != 0;
    float s1 = hi2 ? mx : my;
    float r1 = __shfl_xor(s1, 2);
    float v = (hi2 ? my : mx) + r1;
    v += __shfl_xor(v, 4);
    v += __shfl_xor(v, 8);
    v += __shfl_xor(v, 16);
    v += __shfl_xor(v, 32);

    if (lane < 4) {
      const bool badf = (lane & 1) ? bad_in : bad_lb;
      const float s = badf ? v + kNegInf : v;
      const int slot = ((lane & 1) << 1) | ((lane >> 1) & 1);
      sims[1 + slot * KK + k] = s;
    }
  }
  __syncthreads();

  const float v = sims[1 + tid];
  const float s0 = sims[0];
  float wmax = waveReduceMax(v);
  if (lane == 0) wred[wave] = wmax;
  __syncthreads();
  float m = fmaxf(fmaxf(wred[0], wred[1]), fmaxf(wred[2], wred[3]));
  m = fmaxf(m, s0);
  const float e = expf(v - m);
  float wsum = waveReduceSum(e);
  if (lane == 0) wred[4 + wave] = wsum;
  __syncthreads();
  if (tid == 0) {
    const float tot = wred[4] + wred[5] + wred[6] + wred[7] + expf(s0 - m);
    per_ex[b] = m + logf(tot) - s0;
    if (count_acc) {
      const float max_il = wred[0];
      if (s0 >= max_il) atomicAdd(&stats[0], 1u);
    }
  }
}

// Main pass: one 256-thread block per row b; each 4-lane quad owns one
// negative k. i4 tables: 256B/row, 4x dwordx4 per table row per quad,
// 64 sdot8/lane. Band rows self-fix exactly. The per_ex store and acc
// atomic are issued AFTER the final barrier (fire-and-forget) so no
// barrier drain ever waits on a device-scope memory op (r16/r17 lesson).
__global__ __launch_bounds__(256, 4) void row_i4_kernel(
    const float* __restrict__ ie, const float* __restrict__ le,
    const float* __restrict__ labels, const float* __restrict__ ale,
    const float* __restrict__ al, const unsigned* __restrict__ ie_q,
    const unsigned* __restrict__ le_q, const unsigned* __restrict__ ale_q,
    const float* __restrict__ s_ie, const float* __restrict__ s_le,
    const float* __restrict__ s_ale, const float* __restrict__ sp,
    const unsigned long long* __restrict__ h_lab,
    const unsigned long long* __restrict__ h_al,
    const int* __restrict__ nin, const int* __restrict__ nlb,
    float* __restrict__ per_ex, unsigned* __restrict__ stats) {
  const int b = blockIdx.x;
  const int tid = threadIdx.x;
  const int lane = tid & 63;
  const int wave = tid >> 6;
  const int c = lane & 3;
  const int g = lane >> 2;

  __shared__ unsigned qu[128];         // qi4 (64 u32) + ql4 (64 u32)
  __shared__ float simsX[1 + 4 * KK];  // exact fixup path only
  __shared__ float wred[12];
  __shared__ float pe_sh;
  __shared__ int do_fix, do_acc;

  // Indices + gather loads issued first (before staging barrier).
  const int wuni = __builtin_amdgcn_readfirstlane(wave);
  const int k = wuni * 16 + g;
  const int jl = nlb[b * KK + k];
  const int ji = nin[b * KK + k];

  const u32x4* pa = (const u32x4*)(ale_q + ((size_t)jl << 6)) + c;
  const u32x4* pb = (const u32x4*)(ie_q + ((size_t)ji << 6)) + c;
  const u32x4 A0 = pa[0], A1 = pa[4], A2 = pa[8], A3 = pa[12];
  const u32x4 B0 = pb[0], B1 = pb[4], B2 = pb[8], B3 = pb[12];

  const unsigned long long hb = h_lab[b];
  const bool bad_lb = (h_al[jl] == hb);
  const bool bad_in = (h_lab[ji] == hb);
  const float sA = s_ale[jl];
  const float sB = s_ie[ji];
  const float s0 = sp[b];
  const float sqi = s_ie[b];
  const float sql = s_le[b];

  // Stage the two 256B quantized query rows to LDS (first wave).
  if (wave == 0) {
    qu[lane] = ie_q[((size_t)b << 6) + lane];
    qu[64 + lane] = le_q[((size_t)b << 6) + lane];
  }
  __syncthreads();

  // 64 sdot8 per lane, 4 independent accumulators.
  int il = 0, ll = 0, ii = 0, li = 0;
#define STEP(Ai, Bi, i)                                                \
  {                                                                    \
    const int qb = 4 * c + 16 * (i);                                   \
    const unsigned q0 = qu[qb], q1 = qu[qb + 1];                       \
    const unsigned q2 = qu[qb + 2], q3 = qu[qb + 3];                   \
    const unsigned l0 = qu[64 + qb], l1 = qu[64 + qb + 1];             \
    const unsigned l2 = qu[64 + qb + 2], l3 = qu[64 + qb + 3];         \
    il = sdot8i(Ai.x, q0, il); il = sdot8i(Ai.y, q1, il);              \
    il = sdot8i(Ai.z, q2, il); il = sdot8i(Ai.w, q3, il);              \
    ll = sdot8i(Ai.x, l0, ll); ll = sdot8i(Ai.y, l1, ll);              \
    ll = sdot8i(Ai.z, l2, ll); ll = sdot8i(Ai.w, l3, ll);              \
    ii = sdot8i(Bi.x, q0, ii); ii = sdot8i(Bi.y, q1, ii);              \
    ii = sdot8i(Bi.z, q2, ii); ii = sdot8i(Bi.w, q3, ii);              \
    li = sdot8i(Bi.x, l0, li); li = sdot8i(Bi.y, l1, li);              \
    li = sdot8i(Bi.z, l2, li); li = sdot8i(Bi.w, l3, li);              \
  }
  STEP(A0, B0, 0) STEP(A1, B1, 1) STEP(A2, B2, 2) STEP(A3, B3, 3)
#undef STEP

  // 2-shfl component-split within the quad; c: 0->il 1->ii 2->ll 3->li
  const bool odd = (lane & 1) != 0;
  const int x = odd ? il : ii;
  const int y = odd ? ll : li;
  const int rx = __shfl_xor(x, 1);
  const int ry = __shfl_xor(y, 1);
  const int aa = (odd ? ii : il) + rx;
  const int bb2 = (odd ? li : ll) + ry;
  const bool hi2 = (lane & 2) != 0;
  const int s1 = hi2 ? aa : bb2;
  const int r1 = __shfl_xor(s1, 2);
  const int vi = (hi2 ? bb2 : aa) + r1;

  const float srow = (c & 1) ? sB : sA;
  const float sq = (c & 2) ? sql : sqi;
  const float v = (float)vi * (srow * sq);
  const bool badf = (c & 1) ? bad_in : bad_lb;
  const float s = badf ? v + kNegInf : v;

  // Block LSE from lane-resident sims.
  float m_w = waveReduceMax(s);
  float mil_w = waveReduceMax((c == 0) ? s : -3.0e38f);
  if (lane == 0) {
    wred[wave] = m_w;
    wred[4 + wave] = mil_w;
  }
  __syncthreads();
  float m = fmaxf(fmaxf(fmaxf(wred[0], wred[1]), fmaxf(wred[2], wred[3])), s0);
  const float e = expf(s - m);
  float sum_w = waveReduceSum(e);
  if (lane == 0) wred[8 + wave] = sum_w;
  __syncthreads();
  if (tid == 0) {
    const float tot = wred[8] + wred[9] + wred[10] + wred[11] + expf(s0 - m);
    const float pe = m + logf(tot) - s0;
    const float max_il = fmaxf(fmaxf(wred[4], wred[5]), fmaxf(wred[6], wred[7]));
    const bool wl_row = (pe < kWlPe) || (fabsf(s0 - max_il) < kWlTie);
    pe_sh = pe;
    do_fix = wl_row ? 1 : 0;
    do_acc = (!wl_row && s0 >= max_il) ? 1 : 0;
  }
  __syncthreads();

  if (do_fix) {
    // Exact f32 recompute writes per_ex + counts acc itself.
    row_f32_body(b, ie, le, labels, ale, al, nin, nlb, per_ex, stats,
                 true, simsX, wred);
  } else if (tid == 0) {
    // Fire-and-forget: nothing after this waits on these memory ops.
    per_ex[b] = pe_sh;
    if (do_acc) atomicAdd(&stats[0], 1u);
  }
}

// Fallback: full exact pass (used only if ws too small).
__global__ __launch_bounds__(256) void row_f32_kernel(
    const float* __restrict__ ie, const float* __restrict__ le,
    const float* __restrict__ labels, const float* __restrict__ ale,
    const float* __restrict__ al, const int* __restrict__ nin,
    const int* __restrict__ nlb, float* __restrict__ per_ex,
    unsigned* __restrict__ stats) {
  __shared__ float sims[1 + 4 * KK];
  __shared__ float wred[8];
  row_f32_body(blockIdx.x, ie, le, labels, ale, al, nin, nlb, per_ex, stats,
               true, sims, wred);
}

__global__ __launch_bounds__(256) void finalize_kernel(
    const float* __restrict__ per_ex, const unsigned* __restrict__ stats,
    float* __restrict__ out) {
  __shared__ float pe_s[BB];  // 16 KB
  __shared__ float wred[8];
  const int tid = threadIdx.x;
  const int lane = tid & 63;
  const int wave = tid >> 6;

  float mn = 1.0e30f;
#pragma unroll 4
  for (int i = tid; i < BB; i += 256) {
    const float v = per_ex[i];
    pe_s[i] = v;
    mn = fminf(mn, v);
  }
  mn = waveReduceMin(mn);
  if (lane == 0) wred[wave] = mn;
  __syncthreads();
  const float minpe = fminf(fminf(wred[0], wred[1]), fminf(wred[2], wred[3]));
  const bool scale_on = (minpe < kLn2);  // max(q) > 0.5
  __syncthreads();

  float sum = 0.0f;
#pragma unroll 4
  for (int i = tid; i < BB; i += 256) {
    const float pe = pe_s[i];
    sum += pe * (scale_on ? loss_scale(pe) : 1.0f);
  }
  sum = waveReduceSum(sum);
  if (lane == 0) wred[4 + wave] = sum;
  __syncthreads();
  if (tid == 0) {
    const float tot = wred[4] + wred[5] + wred[6] + wred[7];
    out[0] = tot / (float)BB;
    out[1] = (float)stats[0] / (float)BB;
  }
}

extern "C" void kernel_launch(void* const* d_in, const int* in_sizes, int n_in,
                              void* d_out, int out_size, void* d_ws, size_t ws_size,
                              hipStream_t stream) {
  const float* ie = (const float*)d_in[0];
  const float* le = (const float*)d_in[1];
  const float* labels = (const float*)d_in[2];
  const float* ale = (const float*)d_in[3];
  const float* al = (const float*)d_in[4];
  const int* nin = (const int*)d_in[5];
  const int* nlb = (const int*)d_in[6];
  float* out = (float*)d_out;

  float* per_ex = (float*)d_ws;
  unsigned* stats = (unsigned*)((char*)d_ws + OFF_STATS);

  if (ws_size >= WS_NEED) {
    unsigned* ie_q = (unsigned*)((char*)d_ws + OFF_IEQ);
    unsigned* le_q = (unsigned*)((char*)d_ws + OFF_LEQ);
    unsigned* ale_q = (unsigned*)((char*)d_ws + OFF_ALEQ);
    float* s_ie = (float*)((char*)d_ws + OFF_SIE);
    float* s_le = (float*)((char*)d_ws + OFF_SLE);
    float* s_ale = (float*)((char*)d_ws + OFF_SALE);
    float* sp = (float*)((char*)d_ws + OFF_SP);
    unsigned long long* h_lab = (unsigned long long*)((char*)d_ws + OFF_HLAB);
    unsigned long long* h_al = (unsigned long long*)((char*)d_ws + OFF_HAL);

    const int prep_blocks = (BB + NN) / 4;
    hipLaunchKernelGGL(prep_kernel, dim3(prep_blocks), dim3(256), 0, stream,
                       ie, le, ale, labels, al, ie_q, le_q, ale_q,
                       s_ie, s_le, s_ale, sp, h_lab, h_al, stats);
    hipLaunchKernelGGL(row_i4_kernel, dim3(BB), dim3(256), 0, stream,
                       ie, le, labels, ale, al, ie_q, le_q, ale_q,
                       s_ie, s_le, s_ale, sp, h_lab, h_al, nin, nlb,
                       per_ex, stats);
  } else {
    hipLaunchKernelGGL(init_kernel, dim3(1), dim3(64), 0, stream, stats);
    hipLaunchKernelGGL(row_f32_kernel, dim3(BB), dim3(256), 0, stream,
                       ie, le, labels, ale, al, nin, nlb, per_ex, stats);
  }
  hipLaunchKernelGGL(finalize_kernel, dim3(1), dim3(256), 0, stream,
                     per_ex, stats, out);
}